// Round 24
// baseline (165.204 us; speedup 1.0000x reference)
//
#include <hip/hip_runtime.h>
#include <hip/hip_bf16.h>
#include <stdint.h>
#include <stddef.h>

#define S_LEN 4096
#define DMODEL 1024
#define NHEAD 16
#define HDIM 64
#define L2E 1.4426950408889634f
#define FIXED_M 8.0f

typedef __attribute__((ext_vector_type(8))) short bf16x8;
typedef __attribute__((ext_vector_type(8))) unsigned short u16x8;
typedef __attribute__((ext_vector_type(4))) float f32x4;
typedef __attribute__((ext_vector_type(16))) float f32x16;

__device__ __forceinline__ unsigned short f2bf(float f) {
    unsigned int u = __float_as_uint(f);
    return (unsigned short)((u + 0x7FFFu + ((u >> 16) & 1u)) >> 16);
}
__device__ __forceinline__ float bf2f(unsigned short h) {
    return __uint_as_float(((unsigned int)h) << 16);
}

// async global->LDS, 16B/lane; LDS base wave-uniform, HW adds lane*16 (m97)
__device__ __forceinline__ void gload_lds16(const unsigned short* g, unsigned short* l) {
    __builtin_amdgcn_global_load_lds(
        (const __attribute__((address_space(1))) unsigned int*)g,
        (__attribute__((address_space(3))) unsigned int*)l, 16, 0, 0);
}

// ---------------- fused prep: cvt_wt (blocks 0..1023) | cvt_x (1024..3071) |
// rope table (3072..3583).
__global__ __launch_bounds__(256) void prep_kernel(
    const float* __restrict__ x,
    const float* __restrict__ w0, const float* __restrict__ w1,
    const float* __restrict__ w2, const float* __restrict__ w3,
    unsigned short* __restrict__ xb,
    unsigned short* __restrict__ t0, unsigned short* __restrict__ t1,
    unsigned short* __restrict__ t2, unsigned short* __restrict__ t3,
    float* __restrict__ ctab, float* __restrict__ stab) {
    int bid = blockIdx.x;
    int t = threadIdx.x;
    if (bid < 1024) {                                // ---- W transpose+convert
        const float* src; unsigned short* dst;
        switch (bid >> 8) {
            case 0: src = w0; dst = t0; break;
            case 1: src = w1; dst = t1; break;
            case 2: src = w2; dst = t2; break;
            default: src = w3; dst = t3; break;
        }
        __shared__ float tile[64][65];
        int k0 = ((bid >> 4) & 15) * 64, n0 = (bid & 15) * 64;
        int r = t >> 2, q4 = (t & 3) * 16;
        const float* sp = src + (size_t)(k0 + r) * DMODEL + n0 + q4;
        #pragma unroll
        for (int j = 0; j < 4; ++j) {
            f32x4 v = *(const f32x4*)(sp + j * 4);
            #pragma unroll
            for (int e = 0; e < 4; ++e) tile[r][q4 + j * 4 + e] = v[e];
        }
        __syncthreads();
        int n = t >> 2, kq = (t & 3) * 16;
        unsigned short* dp = dst + (size_t)(n0 + n) * DMODEL + k0 + kq;
        u16x8 a, b;
        #pragma unroll
        for (int j = 0; j < 8; ++j) { a[j] = f2bf(tile[kq + j][n]); b[j] = f2bf(tile[kq + 8 + j][n]); }
        *(u16x8*)dp = a;
        *(u16x8*)(dp + 8) = b;
    } else if (bid < 3072) {                         // ---- x f32 -> bf16
        int i = ((bid - 1024) * 256 + t) * 8;
        f32x4 a = *(const f32x4*)(x + i);
        f32x4 b = *(const f32x4*)(x + i + 4);
        u16x8 o;
        #pragma unroll
        for (int j = 0; j < 4; ++j) { o[j] = f2bf(a[j]); o[4 + j] = f2bf(b[j]); }
        *(u16x8*)(xb + i) = o;
    } else {                                         // ---- RoPE cos/sin table
        int i = (bid - 3072) * 256 + t;
        int s = i >> 5, j = i & 31;
        float freq = exp2f(-0.41524101186092407f * (float)j);   // 10000^(-j/32)
        float ang = (float)s * freq;
        ctab[i] = cosf(ang);
        stab[i] = sinf(ang);
    }
}

// ---------------- GEMM 128x128x64, 4 waves, 16x16x32 bf16 MFMA ----------------
// async global_load_lds staging with rule-21 XOR swizzle (r21, verified).
template<int MODE>
__global__ __launch_bounds__(256) void gemm_kernel(
    const unsigned short* __restrict__ Ab,
    const unsigned short* __restrict__ B0,
    const unsigned short* __restrict__ B1,
    const unsigned short* __restrict__ B2,
    unsigned short* __restrict__ o0,
    unsigned short* __restrict__ o1,
    unsigned short* __restrict__ o2,
    float* __restrict__ fo,
    const float* __restrict__ ctab,
    const float* __restrict__ stab) {
    int z = blockIdx.z;
    const unsigned short* Bt = (MODE == 0) ? B0 : (z == 0 ? B0 : (z == 1 ? B1 : B2));
    unsigned short* outp     = (MODE == 0) ? o0 : (z == 0 ? o0 : (z == 1 ? o1 : o2));
    int m0 = blockIdx.y * 128, n0 = blockIdx.x * 128;
    __shared__ unsigned short As[128][64];
    __shared__ unsigned short Bs[128][64];
    int t = threadIdx.x, w = t >> 6, l = t & 63;
    int wm = w >> 1, wn = w & 1, g = l >> 4, c = l & 15;

    f32x4 acc[4][4];
    #pragma unroll
    for (int m = 0; m < 4; ++m)
        #pragma unroll
        for (int n = 0; n < 4; ++n) acc[m][n] = (f32x4){0.f, 0.f, 0.f, 0.f};

    int srow8 = l >> 3;                 // row within 8-row chunk
    int scs = (l & 7) ^ srow8;          // inverse-swizzled source col block

    for (int kt = 0; kt < DMODEL; kt += 64) {
        __syncthreads();
        #pragma unroll
        for (int ch = 0; ch < 4; ++ch) {
            int qd = w * 4 + ch;        // chunk 0..15, wave-uniform
            gload_lds16(Ab + (size_t)(m0 + qd * 8 + srow8) * DMODEL + kt + scs * 8,
                        (unsigned short*)As + qd * 512);
            gload_lds16(Bt + (size_t)(n0 + qd * 8 + srow8) * DMODEL + kt + scs * 8,
                        (unsigned short*)Bs + qd * 512);
        }
        __syncthreads();                // compiler drains vmcnt before barrier
        #pragma unroll
        for (int kk = 0; kk < 64; kk += 32) {
            bf16x8 af[4], bf[4];
            #pragma unroll
            for (int m = 0; m < 4; ++m) {
                int ra = wm * 64 + m * 16 + c;
                af[m] = *(const bf16x8*)&As[ra][(((kk >> 3) + g) ^ (ra & 7)) << 3];
            }
            #pragma unroll
            for (int n = 0; n < 4; ++n) {
                int rb = wn * 64 + n * 16 + c;
                bf[n] = *(const bf16x8*)&Bs[rb][(((kk >> 3) + g) ^ (rb & 7)) << 3];
            }
            #pragma unroll
            for (int m = 0; m < 4; ++m)
                #pragma unroll
                for (int n = 0; n < 4; ++n)
                    acc[m][n] = __builtin_amdgcn_mfma_f32_16x16x32_bf16(af[m], bf[n], acc[m][n], 0, 0, 0);
        }
    }

    if (MODE == 1 && z < 2) {
        // q: fold 1/sqrt(64) AND log2(e) so attention scores are in log2 domain
        float sc8 = (z == 0) ? 0.125f * L2E : 1.0f;
        #pragma unroll
        for (int m = 0; m < 4; ++m) {
            #pragma unroll
            for (int r = 0; r < 4; ++r) {
                int srow = m0 + wm * 64 + m * 16 + g * 4 + r;
                #pragma unroll
                for (int n = 0; n < 2; ++n) {
                    int e = n * 16 + c;                      // e < 32 within head
                    float cs = ctab[srow * 32 + e];
                    float sn = stab[srow * 32 + e];
                    float lo = acc[m][n][r], hi = acc[m][n + 2][r];
                    float nlo = (lo * cs - hi * sn) * sc8;
                    float nhi = (hi * cs + lo * sn) * sc8;
                    size_t base = (size_t)srow * DMODEL + n0 + wn * 64;
                    outp[base + n * 16 + c]       = f2bf(nlo);
                    outp[base + (n + 2) * 16 + c] = f2bf(nhi);
                }
            }
        }
    } else if (MODE == 1) {
        #pragma unroll
        for (int m = 0; m < 4; ++m)
            #pragma unroll
            for (int r = 0; r < 4; ++r) {
                int srow = m0 + wm * 64 + m * 16 + g * 4 + r;
                size_t base = (size_t)srow * DMODEL + n0 + wn * 64;
                #pragma unroll
                for (int n = 0; n < 4; ++n)
                    outp[base + n * 16 + c] = f2bf(acc[m][n][r]);
            }
    } else {
        #pragma unroll
        for (int m = 0; m < 4; ++m)
            #pragma unroll
            for (int r = 0; r < 4; ++r) {
                int srow = m0 + wm * 64 + m * 16 + g * 4 + r;
                size_t base = (size_t)srow * DMODEL + n0 + wn * 64;
                #pragma unroll
                for (int n = 0; n < 4; ++n)
                    fo[base + n * 16 + c] = acc[m][n][r];
            }
    }
}

// ---------------- causal flash attention, 32x32 swapped-QK^T + swapped-PV ----
// v16: 4 KEY STREAMS x 1024-thread blocks -> 32 waves/CU (was 16; r17-r23 all
// pinned at Occupancy ~35% = 2 blocks/CU x 8 waves). 16 waves = 4 row-groups
// x 4 streams (tiles == ks mod 4), single-buffered per stream with reg
// prefetch (r21 2-barrier pattern at stride 4). LDS 73.7KB -> 2 blocks/CU;
// VGPR capped 64 by launch_bounds(1024,2) = exactly 8 waves/SIMD. Epilogue:
// 4-phase serialized Om2 accumulation + per-row scale in ml2 + 1024-thread
// coalesced store.
__global__ __launch_bounds__(1024, 2) void attn_kernel(
    const unsigned short* __restrict__ q,
    const unsigned short* __restrict__ k,
    const unsigned short* __restrict__ v,
    unsigned short* __restrict__ ctx,      // rows < 2048 written directly
    unsigned short* __restrict__ Opart,    // [2][16][4096][64] bf16 (rows>=2048)
    float* __restrict__ lpart) {           // [2][16][4096]
    int h = blockIdx.x;
    int pair = blockIdx.y;                           // 0..15
    int p = blockIdx.z;
    int t = threadIdx.x, w = t >> 6, l = t & 63, c = l & 31, hi = l >> 5;
    int rg = w & 3, ks = w >> 2;                     // row-group, key-stream 0..3

    __shared__ __align__(16) char smraw[73728];
    unsigned short (*KsT)[64][72] = (unsigned short (*)[64][72])smraw;           // [4][64][72]
    unsigned short (*VtT)[64][72] = (unsigned short (*)[64][72])(smraw + 36864); // [4][64][72]
    float (*Om2)[66] = (float (*)[66])smraw;                                     // [128][66]
    float* ml2       = (float*)(smraw + 33792);                                  // [128]

    int ts = t & 255;                                // id within my stream
    int skr = ts >> 2, skc = (ts & 3) * 16;
    int svr = ts & 63, svc = ((ts >> 6) & 3) * 16;
    int svp = (svr & ~0xC) | ((svr & 4) << 1) | ((svr & 8) >> 1);  // pi(key)
    const unsigned short* gkb = k + (size_t)skr * DMODEL + h * HDIM + skc;
    const unsigned short* gvb = v + (size_t)svr * DMODEL + h * HDIM + svc;

    auto run_segment = [&](int qb, int t0, int cnt, bool finalize) {
        int qrow = qb * 128 + rg * 32 + c;
        int wrmax = qb * 128 + rg * 32 + 31;

        bf16x8 qf[4];
        {
            const unsigned short* qp = q + (size_t)qrow * DMODEL + h * HDIM + hi * 8;
            #pragma unroll
            for (int s = 0; s < 4; ++s) qf[s] = *(const bf16x8*)(qp + s * 16);
        }
        f32x16 o0, o1;
        #pragma unroll
        for (int i = 0; i < 16; ++i) { o0[i] = 0.f; o1[i] = 0.f; }
        float lsum = 0.f;

        u16x8 ka, kb, va, vb;
        if (ks < cnt) {                              // prologue: tile t0+ks
            size_t off = (size_t)((t0 + ks) * 64) * DMODEL;
            ka = *(const u16x8*)(gkb + off);
            kb = *(const u16x8*)(gkb + off + 8);
            va = *(const u16x8*)(gvb + off);
            vb = *(const u16x8*)(gvb + off + 8);
            *(u16x8*)&KsT[ks][skr][skc]     = ka;
            *(u16x8*)&KsT[ks][skr][skc + 8] = kb;
            #pragma unroll
            for (int j = 0; j < 8; ++j) {
                VtT[ks][svc + j][svp]     = va[j];
                VtT[ks][svc + 8 + j][svp] = vb[j];
            }
        }

        int NIT = (cnt + 3) >> 2;
        for (int it = 0; it < NIT; ++it) {
            int j = 4 * it + ks;                     // my stream's local tile
            int kv0 = (t0 + j) * 64;
            if (j + 4 < cnt) {                       // prefetch tile t0+j+4
                size_t off = (size_t)(kv0 + 256) * DMODEL;
                ka = *(const u16x8*)(gkb + off);
                kb = *(const u16x8*)(gkb + off + 8);
                va = *(const u16x8*)(gvb + off);
                vb = *(const u16x8*)(gvb + off + 8);
            }
            __syncthreads();                         // tiles staged

            if (j < cnt) {
                #pragma unroll
                for (int h2 = 0; h2 < 2; ++h2) {
                    int kbase = kv0 + h2 * 32;
                    if (kbase > wrmax) continue;     // fully-masked half

                    f32x16 sf;
                    #pragma unroll
                    for (int i = 0; i < 16; ++i) sf[i] = 0.f;
                    __builtin_amdgcn_s_setprio(1);
                    #pragma unroll
                    for (int s = 0; s < 4; ++s) {
                        bf16x8 kf = *(const bf16x8*)&KsT[ks][h2 * 32 + c][s * 16 + hi * 8];
                        sf = __builtin_amdgcn_mfma_f32_32x32x16_bf16(kf, qf[s], sf, 0, 0, 0);
                    }
                    __builtin_amdgcn_s_setprio(0);

                    if (kbase + 31 >= wrmax) {       // diagonal half: causal mask
                        #pragma unroll
                        for (int r = 0; r < 16; ++r) {
                            int key = kbase + (r & 3) + 8 * (r >> 2) + 4 * hi;
                            if (key > qrow) sf[r] = -3.0e38f;
                        }
                    }

                    // P = 2^(s - FIXED_M); RNE pair-pack; B-operand = regs as-is
                    float ps = 0.f;
                    union { unsigned int u[8]; bf16x8 v[2]; } pu;
                    #pragma unroll
                    for (int jj = 0; jj < 8; ++jj) {
                        float p0 = exp2f(sf[2 * jj]     - FIXED_M);
                        float p1 = exp2f(sf[2 * jj + 1] - FIXED_M);
                        ps += p0 + p1;
                        union { struct { __hip_bfloat16 x, y; } hh; unsigned int u; } cv;
                        cv.hh.x = __float2bfloat16(p0);
                        cv.hh.y = __float2bfloat16(p1);
                        pu.u[jj] = cv.u;
                    }
                    lsum += ps;                      // cross-half reduce deferred

                    // O^T += V^T x P^T  (A = permuted-Vt rows, B = P regs)
                    __builtin_amdgcn_s_setprio(1);
                    {
                        bf16x8 a00 = *(const bf16x8*)&VtT[ks][c][h2 * 32 + hi * 8];
                        bf16x8 a01 = *(const bf16x8*)&VtT[ks][c][h2 * 32 + 16 + hi * 8];
                        bf16x8 a10 = *(const bf16x8*)&VtT[ks][32 + c][h2 * 32 + hi * 8];
                        bf16x8 a11 = *(const bf16x8*)&VtT[ks][32 + c][h2 * 32 + 16 + hi * 8];
                        o0 = __builtin_amdgcn_mfma_f32_32x32x16_bf16(a00, pu.v[0], o0, 0, 0, 0);
                        o0 = __builtin_amdgcn_mfma_f32_32x32x16_bf16(a01, pu.v[1], o0, 0, 0, 0);
                        o1 = __builtin_amdgcn_mfma_f32_32x32x16_bf16(a10, pu.v[0], o1, 0, 0, 0);
                        o1 = __builtin_amdgcn_mfma_f32_32x32x16_bf16(a11, pu.v[1], o1, 0, 0, 0);
                    }
                    __builtin_amdgcn_s_setprio(0);
                }
            }

            if (it + 1 < NIT) {
                __syncthreads();                     // all waves done with LDS
                if (j + 4 < cnt) {
                    *(u16x8*)&KsT[ks][skr][skc]     = ka;
                    *(u16x8*)&KsT[ks][skr][skc + 8] = kb;
                    #pragma unroll
                    for (int jj = 0; jj < 8; ++jj) {
                        VtT[ks][svc + jj][svp]     = va[jj];
                        VtT[ks][svc + 8 + jj][svp] = vb[jj];
                    }
                }
            }
        }

        lsum += __shfl_xor(lsum, 32, 64);            // single cross-half reduce

        __syncthreads();                             // tile LDS dead; Om2 aliases
        if (ks == 0) {                               // phase 0: write
            #pragma unroll
            for (int r = 0; r < 16; ++r) {
                int dim = (r & 3) + 8 * (r >> 2) + 4 * hi;
                Om2[rg * 32 + c][dim]      = o0[r];
                Om2[rg * 32 + c][dim + 32] = o1[r];
            }
            if (hi == 0) ml2[rg * 32 + c] = lsum;
        }
        __syncthreads();
        if (ks == 1) {                               // phase 1: accumulate
            #pragma unroll
            for (int r = 0; r < 16; ++r) {
                int dim = (r & 3) + 8 * (r >> 2) + 4 * hi;
                Om2[rg * 32 + c][dim]      += o0[r];
                Om2[rg * 32 + c][dim + 32] += o1[r];
            }
            if (hi == 0) ml2[rg * 32 + c] += lsum;
        }
        __syncthreads();
        if (ks == 2) {                               // phase 2: accumulate
            #pragma unroll
            for (int r = 0; r < 16; ++r) {
                int dim = (r & 3) + 8 * (r >> 2) + 4 * hi;
                Om2[rg * 32 + c][dim]      += o0[r];
                Om2[rg * 32 + c][dim + 32] += o1[r];
            }
            if (hi == 0) ml2[rg * 32 + c] += lsum;
        }
        __syncthreads();
        if (ks == 3) {                               // phase 3: accumulate + scale
            #pragma unroll
            for (int r = 0; r < 16; ++r) {
                int dim = (r & 3) + 8 * (r >> 2) + 4 * hi;
                Om2[rg * 32 + c][dim]      += o0[r];
                Om2[rg * 32 + c][dim + 32] += o1[r];
            }
            if (hi == 0) {
                float lc = ml2[rg * 32 + c] + lsum;
                ml2[rg * 32 + c] = finalize ? 1.0f / lc : 1.0f;
                if (!finalize)
                    lpart[(size_t)(p * 16 + h) * 4096 + qrow] = lc;
            }
        }
        __syncthreads();
        {   // cooperative store: thread t -> row t>>3, dims (t&7)*8..+7 (16B)
            int row = t >> 3, d0 = (t & 7) * 8;
            float sc = ml2[row];
            u16x8 oa;
            #pragma unroll
            for (int j = 0; j < 8; ++j)
                oa[j] = f2bf(Om2[row][d0 + j] * sc);
            if (finalize) {
                size_t cb = (size_t)(qb * 128 + row) * DMODEL + h * HDIM + d0;
                *(u16x8*)&ctx[cb] = oa;
            } else {
                size_t obase = ((size_t)(p * 16 + h) * 4096 + qb * 128 + row) * 64 + d0;
                *(u16x8*)&Opart[obase] = oa;
            }
        }
        __syncthreads();                             // Om2 reads done before next
    };                                               // segment stages into KsT

    if (p == 0) {
        run_segment(pair, 0, 2 * pair + 2, true);            // qbA, finalized
        run_segment(31 - pair, 0, 31 - 2 * pair, false);     // qbB head partial
    } else {
        run_segment(31 - pair, 31 - 2 * pair, 33, false);    // qbB tail partial
    }
}

// ---------------- merge the two key partitions (rows >= 2048) -> ctx --------
__global__ __launch_bounds__(256) void attn_merge_kernel(
    const unsigned short* __restrict__ Op,   // [2][16][4096][64]
    const float* __restrict__ lp,            // [2][16][4096]
    unsigned short* __restrict__ ctx) {      // [4096][1024]
    int i = blockIdx.x * 256 + threadIdx.x;  // 16*2048*8
    int g8 = i & 7;
    int row = 2048 + ((i >> 3) & 2047);
    int h = i >> 14;
    size_t idx = (size_t)h * 4096 + row;
    const size_t PS = (size_t)16 * 4096;
    float inv = 1.0f / (lp[idx] + lp[PS + idx]);
    u16x8 v0 = *(const u16x8*)(Op + idx * 64 + g8 * 8);
    u16x8 v1 = *(const u16x8*)(Op + (PS + idx) * 64 + g8 * 8);
    u16x8 o;
    #pragma unroll
    for (int j = 0; j < 8; ++j)
        o[j] = f2bf((bf2f(v0[j]) + bf2f(v1[j])) * inv);
    *(u16x8*)(ctx + (size_t)row * DMODEL + h * 64 + g8 * 8) = o;
}

extern "C" void kernel_launch(void* const* d_in, const int* in_sizes, int n_in,
                              void* d_out, int out_size, void* d_ws, size_t ws_size,
                              hipStream_t stream) {
    const float* x  = (const float*)d_in[0];
    // d_in[1] = causal mask (tril by construction) — unused
    const float* Wq = (const float*)d_in[2];
    const float* Wk = (const float*)d_in[3];
    const float* Wv = (const float*)d_in[4];
    const float* Wo = (const float*)d_in[5];

    // ws layout (peak 60 MB; ws >= 64 MB verified r3/r4):
    //   [0,0.5M) ctab  [0.5M,1M) stab
    //   [1M,9M)  ctx  (attn writes rows<2048 direct; merge writes rows>=2048)
    //   [1M,3M) Wtq  [3M,5M) Wtk  [5M,7M) Wtv   (dead before attn)
    //   [9M,11M) Wto
    //   [11M,19M) kr  [19M,27M) vb  [27M,35M) qr  [35M,43M) xb
    //   [43M,59M) Opart (bf16, 2 partitions)  [59M,60M) lpart (f32)
    char* ws = (char*)d_ws;
    float* ctab = (float*)(ws);
    float* stab = (float*)(ws + (512u << 10));
    unsigned short* ctx = (unsigned short*)(ws + (1u  << 20));
    unsigned short* Wtq = (unsigned short*)(ws + (1u  << 20));
    unsigned short* Wtk = (unsigned short*)(ws + (3u  << 20));
    unsigned short* Wtv = (unsigned short*)(ws + (5u  << 20));
    unsigned short* Wto = (unsigned short*)(ws + (9u  << 20));
    unsigned short* kr  = (unsigned short*)(ws + (11u << 20));
    unsigned short* vb  = (unsigned short*)(ws + (19u << 20));
    unsigned short* qr  = (unsigned short*)(ws + (27u << 20));
    unsigned short* xb  = (unsigned short*)(ws + (35u << 20));
    unsigned short* Opart = (unsigned short*)(ws + (43u << 20));
    float* lpart = (float*)(ws + (59u << 20));

    prep_kernel<<<3584, 256, 0, stream>>>(x, Wq, Wk, Wv, Wo, xb,
                                          Wtq, Wtk, Wtv, Wto, ctab, stab);
    gemm_kernel<1><<<dim3(8, 32, 3), 256, 0, stream>>>(xb, Wtq, Wtk, Wtv,
                                                       qr, kr, vb, nullptr, ctab, stab);
    attn_kernel<<<dim3(16, 16, 2), 1024, 0, stream>>>(qr, kr, vb, ctx, Opart, lpart);
    attn_merge_kernel<<<(16 * 2048 * 8) / 256, 256, 0, stream>>>(Opart, lpart, ctx);
    gemm_kernel<0><<<dim3(8, 32, 1), 256, 0, stream>>>(ctx, Wto, nullptr, nullptr,
                                                       nullptr, nullptr, nullptr,
                                                       (float*)d_out, ctab, stab);
}

// Round 25
// 150.781 us; speedup vs baseline: 1.0957x; 1.0957x over previous
//
#include <hip/hip_runtime.h>
#include <hip/hip_bf16.h>
#include <stdint.h>
#include <stddef.h>

#define S_LEN 4096
#define DMODEL 1024
#define NHEAD 16
#define HDIM 64
#define L2E 1.4426950408889634f
#define FIXED_M 8.0f

typedef __attribute__((ext_vector_type(8))) short bf16x8;
typedef __attribute__((ext_vector_type(8))) unsigned short u16x8;
typedef __attribute__((ext_vector_type(4))) float f32x4;
typedef __attribute__((ext_vector_type(16))) float f32x16;

__device__ __forceinline__ unsigned short f2bf(float f) {
    unsigned int u = __float_as_uint(f);
    return (unsigned short)((u + 0x7FFFu + ((u >> 16) & 1u)) >> 16);
}
__device__ __forceinline__ float bf2f(unsigned short h) {
    return __uint_as_float(((unsigned int)h) << 16);
}

// async global->LDS, 16B/lane; LDS base wave-uniform, HW adds lane*16 (m97)
__device__ __forceinline__ void gload_lds16(const unsigned short* g, unsigned short* l) {
    __builtin_amdgcn_global_load_lds(
        (const __attribute__((address_space(1))) unsigned int*)g,
        (__attribute__((address_space(3))) unsigned int*)l, 16, 0, 0);
}

// ---------------- fused prep: cvt_wt (blocks 0..1023) | cvt_x (1024..3071) |
// rope table (3072..3583).
__global__ __launch_bounds__(256) void prep_kernel(
    const float* __restrict__ x,
    const float* __restrict__ w0, const float* __restrict__ w1,
    const float* __restrict__ w2, const float* __restrict__ w3,
    unsigned short* __restrict__ xb,
    unsigned short* __restrict__ t0, unsigned short* __restrict__ t1,
    unsigned short* __restrict__ t2, unsigned short* __restrict__ t3,
    float* __restrict__ ctab, float* __restrict__ stab) {
    int bid = blockIdx.x;
    int t = threadIdx.x;
    if (bid < 1024) {                                // ---- W transpose+convert
        const float* src; unsigned short* dst;
        switch (bid >> 8) {
            case 0: src = w0; dst = t0; break;
            case 1: src = w1; dst = t1; break;
            case 2: src = w2; dst = t2; break;
            default: src = w3; dst = t3; break;
        }
        __shared__ float tile[64][65];
        int k0 = ((bid >> 4) & 15) * 64, n0 = (bid & 15) * 64;
        int r = t >> 2, q4 = (t & 3) * 16;
        const float* sp = src + (size_t)(k0 + r) * DMODEL + n0 + q4;
        #pragma unroll
        for (int j = 0; j < 4; ++j) {
            f32x4 v = *(const f32x4*)(sp + j * 4);
            #pragma unroll
            for (int e = 0; e < 4; ++e) tile[r][q4 + j * 4 + e] = v[e];
        }
        __syncthreads();
        int n = t >> 2, kq = (t & 3) * 16;
        unsigned short* dp = dst + (size_t)(n0 + n) * DMODEL + k0 + kq;
        u16x8 a, b;
        #pragma unroll
        for (int j = 0; j < 8; ++j) { a[j] = f2bf(tile[kq + j][n]); b[j] = f2bf(tile[kq + 8 + j][n]); }
        *(u16x8*)dp = a;
        *(u16x8*)(dp + 8) = b;
    } else if (bid < 3072) {                         // ---- x f32 -> bf16
        int i = ((bid - 1024) * 256 + t) * 8;
        f32x4 a = *(const f32x4*)(x + i);
        f32x4 b = *(const f32x4*)(x + i + 4);
        u16x8 o;
        #pragma unroll
        for (int j = 0; j < 4; ++j) { o[j] = f2bf(a[j]); o[4 + j] = f2bf(b[j]); }
        *(u16x8*)(xb + i) = o;
    } else {                                         // ---- RoPE cos/sin table
        int i = (bid - 3072) * 256 + t;
        int s = i >> 5, j = i & 31;
        float freq = exp2f(-0.41524101186092407f * (float)j);   // 10000^(-j/32)
        float ang = (float)s * freq;
        ctab[i] = cosf(ang);
        stab[i] = sinf(ang);
    }
}

// ---------------- GEMM 128x128x64, 4 waves, 16x16x32 bf16 MFMA ----------------
// async global_load_lds staging with rule-21 XOR swizzle (r21, verified).
template<int MODE>
__global__ __launch_bounds__(256) void gemm_kernel(
    const unsigned short* __restrict__ Ab,
    const unsigned short* __restrict__ B0,
    const unsigned short* __restrict__ B1,
    const unsigned short* __restrict__ B2,
    unsigned short* __restrict__ o0,
    unsigned short* __restrict__ o1,
    unsigned short* __restrict__ o2,
    float* __restrict__ fo,
    const float* __restrict__ ctab,
    const float* __restrict__ stab) {
    int z = blockIdx.z;
    const unsigned short* Bt = (MODE == 0) ? B0 : (z == 0 ? B0 : (z == 1 ? B1 : B2));
    unsigned short* outp     = (MODE == 0) ? o0 : (z == 0 ? o0 : (z == 1 ? o1 : o2));
    int m0 = blockIdx.y * 128, n0 = blockIdx.x * 128;
    __shared__ unsigned short As[128][64];
    __shared__ unsigned short Bs[128][64];
    int t = threadIdx.x, w = t >> 6, l = t & 63;
    int wm = w >> 1, wn = w & 1, g = l >> 4, c = l & 15;

    f32x4 acc[4][4];
    #pragma unroll
    for (int m = 0; m < 4; ++m)
        #pragma unroll
        for (int n = 0; n < 4; ++n) acc[m][n] = (f32x4){0.f, 0.f, 0.f, 0.f};

    int srow8 = l >> 3;                 // row within 8-row chunk
    int scs = (l & 7) ^ srow8;          // inverse-swizzled source col block

    for (int kt = 0; kt < DMODEL; kt += 64) {
        __syncthreads();
        #pragma unroll
        for (int ch = 0; ch < 4; ++ch) {
            int qd = w * 4 + ch;        // chunk 0..15, wave-uniform
            gload_lds16(Ab + (size_t)(m0 + qd * 8 + srow8) * DMODEL + kt + scs * 8,
                        (unsigned short*)As + qd * 512);
            gload_lds16(Bt + (size_t)(n0 + qd * 8 + srow8) * DMODEL + kt + scs * 8,
                        (unsigned short*)Bs + qd * 512);
        }
        __syncthreads();                // compiler drains vmcnt before barrier
        #pragma unroll
        for (int kk = 0; kk < 64; kk += 32) {
            bf16x8 af[4], bf[4];
            #pragma unroll
            for (int m = 0; m < 4; ++m) {
                int ra = wm * 64 + m * 16 + c;
                af[m] = *(const bf16x8*)&As[ra][(((kk >> 3) + g) ^ (ra & 7)) << 3];
            }
            #pragma unroll
            for (int n = 0; n < 4; ++n) {
                int rb = wn * 64 + n * 16 + c;
                bf[n] = *(const bf16x8*)&Bs[rb][(((kk >> 3) + g) ^ (rb & 7)) << 3];
            }
            #pragma unroll
            for (int m = 0; m < 4; ++m)
                #pragma unroll
                for (int n = 0; n < 4; ++n)
                    acc[m][n] = __builtin_amdgcn_mfma_f32_16x16x32_bf16(af[m], bf[n], acc[m][n], 0, 0, 0);
        }
    }

    if (MODE == 1 && z < 2) {
        // q: fold 1/sqrt(64) AND log2(e) so attention scores are in log2 domain
        float sc8 = (z == 0) ? 0.125f * L2E : 1.0f;
        #pragma unroll
        for (int m = 0; m < 4; ++m) {
            #pragma unroll
            for (int r = 0; r < 4; ++r) {
                int srow = m0 + wm * 64 + m * 16 + g * 4 + r;
                #pragma unroll
                for (int n = 0; n < 2; ++n) {
                    int e = n * 16 + c;                      // e < 32 within head
                    float cs = ctab[srow * 32 + e];
                    float sn = stab[srow * 32 + e];
                    float lo = acc[m][n][r], hi = acc[m][n + 2][r];
                    float nlo = (lo * cs - hi * sn) * sc8;
                    float nhi = (hi * cs + lo * sn) * sc8;
                    size_t base = (size_t)srow * DMODEL + n0 + wn * 64;
                    outp[base + n * 16 + c]       = f2bf(nlo);
                    outp[base + (n + 2) * 16 + c] = f2bf(nhi);
                }
            }
        }
    } else if (MODE == 1) {
        #pragma unroll
        for (int m = 0; m < 4; ++m)
            #pragma unroll
            for (int r = 0; r < 4; ++r) {
                int srow = m0 + wm * 64 + m * 16 + g * 4 + r;
                size_t base = (size_t)srow * DMODEL + n0 + wn * 64;
                #pragma unroll
                for (int n = 0; n < 4; ++n)
                    outp[base + n * 16 + c] = f2bf(acc[m][n][r]);
            }
    } else {
        #pragma unroll
        for (int m = 0; m < 4; ++m)
            #pragma unroll
            for (int r = 0; r < 4; ++r) {
                int srow = m0 + wm * 64 + m * 16 + g * 4 + r;
                size_t base = (size_t)srow * DMODEL + n0 + wn * 64;
                #pragma unroll
                for (int n = 0; n < 4; ++n)
                    fo[base + n * 16 + c] = acc[m][n][r];
            }
    }
}

// ---------------- causal flash attention, 32x32 swapped-QK^T + swapped-PV ----
// r23 version (best measured): uniform triangle pairs, double-buffered K/V
// tiles -> one barrier/iteration, O^T = V^T x P^T with pi(key) staging
// scatter, lane-local inv, coalesced epilogue.
__global__ __launch_bounds__(512, 4) void attn_kernel(
    const unsigned short* __restrict__ q,
    const unsigned short* __restrict__ k,
    const unsigned short* __restrict__ v,
    unsigned short* __restrict__ ctx,      // rows < 2048 written directly
    unsigned short* __restrict__ Opart,    // [2][16][4096][64] bf16 (rows>=2048)
    float* __restrict__ lpart) {           // [2][16][4096]
    int h = blockIdx.x;
    int pair = blockIdx.y;                           // 0..15
    int p = blockIdx.z;
    int t = threadIdx.x, w = t >> 6, l = t & 63, c = l & 31, hi = l >> 5;
    int rg = w & 3, ks = w >> 2;                     // row-group, key-stream

    __shared__ __align__(16) char smraw[73728];
    // [buf][ks][64][72] for K and V
    unsigned short (*KsT)[2][64][72] = (unsigned short (*)[2][64][72])smraw;
    unsigned short (*VtT)[2][64][72] = (unsigned short (*)[2][64][72])(smraw + 36864);
    float (*Om2)[66] = (float (*)[66])smraw;                                     // [128][66]
    float* ml2       = (float*)(smraw + 33792);                                  // [128]

    int ts = t & 255;
    int skr = ts >> 2, skc = (ts & 3) * 16;
    int svr = ts & 63, svc = ((ts >> 6) & 3) * 16;
    int svp = (svr & ~0xC) | ((svr & 4) << 1) | ((svr & 8) >> 1);  // pi(key)
    const unsigned short* gkb = k + (size_t)skr * DMODEL + h * HDIM + skc;
    const unsigned short* gvb = v + (size_t)svr * DMODEL + h * HDIM + svc;

    auto run_segment = [&](int qb, int t0, int cnt, bool finalize) {
        int qrow = qb * 128 + rg * 32 + c;
        int wrmax = qb * 128 + rg * 32 + 31;

        bf16x8 qf[4];
        {
            const unsigned short* qp = q + (size_t)qrow * DMODEL + h * HDIM + hi * 8;
            #pragma unroll
            for (int s = 0; s < 4; ++s) qf[s] = *(const bf16x8*)(qp + s * 16);
        }
        f32x16 o0, o1;
        #pragma unroll
        for (int i = 0; i < 16; ++i) { o0[i] = 0.f; o1[i] = 0.f; }
        float lsum = 0.f;

        u16x8 ka, kb, va, vb;
        if (ks < cnt) {                              // prologue: tile t0+ks -> buf0
            size_t off = (size_t)((t0 + ks) * 64) * DMODEL;
            ka = *(const u16x8*)(gkb + off);
            kb = *(const u16x8*)(gkb + off + 8);
            va = *(const u16x8*)(gvb + off);
            vb = *(const u16x8*)(gvb + off + 8);
            *(u16x8*)&KsT[0][ks][skr][skc]     = ka;
            *(u16x8*)&KsT[0][ks][skr][skc + 8] = kb;
            #pragma unroll
            for (int j = 0; j < 8; ++j) {
                VtT[0][ks][svc + j][svp]     = va[j];
                VtT[0][ks][svc + 8 + j][svp] = vb[j];
            }
        }
        __syncthreads();                             // buf0 staged

        int NIT = (cnt + 1) >> 1;
        for (int it = 0; it < NIT; ++it) {
            int j = 2 * it + ks;                     // local tile index
            int buf = it & 1;
            int kv0 = (t0 + j) * 64;
            if (j + 2 < cnt) {                       // issue loads for tile t0+j+2
                size_t off = (size_t)(kv0 + 128) * DMODEL;
                ka = *(const u16x8*)(gkb + off);
                kb = *(const u16x8*)(gkb + off + 8);
                va = *(const u16x8*)(gvb + off);
                vb = *(const u16x8*)(gvb + off + 8);
            }

            if (j < cnt) {
                #pragma unroll
                for (int h2 = 0; h2 < 2; ++h2) {
                    int kbase = kv0 + h2 * 32;
                    if (kbase > wrmax) continue;     // fully-masked half

                    f32x16 sf;
                    #pragma unroll
                    for (int i = 0; i < 16; ++i) sf[i] = 0.f;
                    __builtin_amdgcn_s_setprio(1);
                    #pragma unroll
                    for (int s = 0; s < 4; ++s) {
                        bf16x8 kf = *(const bf16x8*)&KsT[buf][ks][h2 * 32 + c][s * 16 + hi * 8];
                        sf = __builtin_amdgcn_mfma_f32_32x32x16_bf16(kf, qf[s], sf, 0, 0, 0);
                    }
                    __builtin_amdgcn_s_setprio(0);

                    if (kbase + 31 >= wrmax) {       // diagonal half: causal mask
                        #pragma unroll
                        for (int r = 0; r < 16; ++r) {
                            int key = kbase + (r & 3) + 8 * (r >> 2) + 4 * hi;
                            if (key > qrow) sf[r] = -3.0e38f;
                        }
                    }

                    // P = 2^(s - FIXED_M); RNE pair-pack; B-operand = regs as-is
                    float ps = 0.f;
                    union { unsigned int u[8]; bf16x8 v[2]; } pu;
                    #pragma unroll
                    for (int jj = 0; jj < 8; ++jj) {
                        float p0 = exp2f(sf[2 * jj]     - FIXED_M);
                        float p1 = exp2f(sf[2 * jj + 1] - FIXED_M);
                        ps += p0 + p1;
                        union { struct { __hip_bfloat16 x, y; } hh; unsigned int u; } cv;
                        cv.hh.x = __float2bfloat16(p0);
                        cv.hh.y = __float2bfloat16(p1);
                        pu.u[jj] = cv.u;
                    }
                    lsum += ps;                      // cross-half reduce deferred

                    // O^T += V^T x P^T  (A = permuted-Vt rows, B = P regs)
                    __builtin_amdgcn_s_setprio(1);
                    {
                        bf16x8 a00 = *(const bf16x8*)&VtT[buf][ks][c][h2 * 32 + hi * 8];
                        bf16x8 a01 = *(const bf16x8*)&VtT[buf][ks][c][h2 * 32 + 16 + hi * 8];
                        bf16x8 a10 = *(const bf16x8*)&VtT[buf][ks][32 + c][h2 * 32 + hi * 8];
                        bf16x8 a11 = *(const bf16x8*)&VtT[buf][ks][32 + c][h2 * 32 + 16 + hi * 8];
                        o0 = __builtin_amdgcn_mfma_f32_32x32x16_bf16(a00, pu.v[0], o0, 0, 0, 0);
                        o0 = __builtin_amdgcn_mfma_f32_32x32x16_bf16(a01, pu.v[1], o0, 0, 0, 0);
                        o1 = __builtin_amdgcn_mfma_f32_32x32x16_bf16(a10, pu.v[0], o1, 0, 0, 0);
                        o1 = __builtin_amdgcn_mfma_f32_32x32x16_bf16(a11, pu.v[1], o1, 0, 0, 0);
                    }
                    __builtin_amdgcn_s_setprio(0);
                }
            }

            if (j + 2 < cnt) {                       // write tile t0+j+2 -> buf^1
                *(u16x8*)&KsT[buf ^ 1][ks][skr][skc]     = ka;
                *(u16x8*)&KsT[buf ^ 1][ks][skr][skc + 8] = kb;
                #pragma unroll
                for (int jj = 0; jj < 8; ++jj) {
                    VtT[buf ^ 1][ks][svc + jj][svp]     = va[jj];
                    VtT[buf ^ 1][ks][svc + 8 + jj][svp] = vb[jj];
                }
            }
            __syncthreads();                         // single barrier / iteration
        }

        lsum += __shfl_xor(lsum, 32, 64);            // single cross-half reduce

        // (last loop barrier already separates tile reads from Om2 aliasing)
        if (ks == 0) {
            #pragma unroll
            for (int r = 0; r < 16; ++r) {
                int dim = (r & 3) + 8 * (r >> 2) + 4 * hi;
                Om2[rg * 32 + c][dim]      = o0[r];
                Om2[rg * 32 + c][dim + 32] = o1[r];
            }
            if (hi == 0) ml2[rg * 32 + c] = lsum;
        }
        __syncthreads();
        if (ks == 1) {
            float lc = ml2[rg * 32 + c] + lsum;
            float sc = finalize ? 1.0f / lc : 1.0f;  // inv is lane-local
            #pragma unroll
            for (int r = 0; r < 16; ++r) {
                int dim = (r & 3) + 8 * (r >> 2) + 4 * hi;
                Om2[rg * 32 + c][dim]      = (Om2[rg * 32 + c][dim]      + o0[r]) * sc;
                Om2[rg * 32 + c][dim + 32] = (Om2[rg * 32 + c][dim + 32] + o1[r]) * sc;
            }
            if (!finalize && hi == 0)
                lpart[(size_t)(p * 16 + h) * 4096 + qrow] = lc;
        }
        __syncthreads();
        {   // cooperative coalesced store: thread t -> row t>>2, dims (t&3)*16..+15
            int row = t >> 2, d0 = (t & 3) * 16;
            u16x8 oa, ob;
            #pragma unroll
            for (int j = 0; j < 8; ++j) {
                oa[j] = f2bf(Om2[row][d0 + j]);
                ob[j] = f2bf(Om2[row][d0 + 8 + j]);
            }
            if (finalize) {
                size_t cb = (size_t)(qb * 128 + row) * DMODEL + h * HDIM + d0;
                *(u16x8*)&ctx[cb]     = oa;
                *(u16x8*)&ctx[cb + 8] = ob;
            } else {
                size_t obase = ((size_t)(p * 16 + h) * 4096 + qb * 128 + row) * 64 + d0;
                *(u16x8*)&Opart[obase]     = oa;
                *(u16x8*)&Opart[obase + 8] = ob;
            }
        }
        __syncthreads();                             // Om2 reads done before next
    };                                               // segment stages into buf0

    if (p == 0) {
        run_segment(pair, 0, 2 * pair + 2, true);            // qbA, finalized
        run_segment(31 - pair, 0, 31 - 2 * pair, false);     // qbB head partial
    } else {
        run_segment(31 - pair, 31 - 2 * pair, 33, false);    // qbB tail partial
    }
}

// ---------------- merge the two key partitions (rows >= 2048) -> ctx --------
__global__ __launch_bounds__(256) void attn_merge_kernel(
    const unsigned short* __restrict__ Op,   // [2][16][4096][64]
    const float* __restrict__ lp,            // [2][16][4096]
    unsigned short* __restrict__ ctx) {      // [4096][1024]
    int i = blockIdx.x * 256 + threadIdx.x;  // 16*2048*8
    int g8 = i & 7;
    int row = 2048 + ((i >> 3) & 2047);
    int h = i >> 14;
    size_t idx = (size_t)h * 4096 + row;
    const size_t PS = (size_t)16 * 4096;
    float inv = 1.0f / (lp[idx] + lp[PS + idx]);
    u16x8 v0 = *(const u16x8*)(Op + idx * 64 + g8 * 8);
    u16x8 v1 = *(const u16x8*)(Op + (PS + idx) * 64 + g8 * 8);
    u16x8 o;
    #pragma unroll
    for (int j = 0; j < 8; ++j)
        o[j] = f2bf((bf2f(v0[j]) + bf2f(v1[j])) * inv);
    *(u16x8*)(ctx + (size_t)row * DMODEL + h * 64 + g8 * 8) = o;
}

extern "C" void kernel_launch(void* const* d_in, const int* in_sizes, int n_in,
                              void* d_out, int out_size, void* d_ws, size_t ws_size,
                              hipStream_t stream) {
    const float* x  = (const float*)d_in[0];
    // d_in[1] = causal mask (tril by construction) — unused
    const float* Wq = (const float*)d_in[2];
    const float* Wk = (const float*)d_in[3];
    const float* Wv = (const float*)d_in[4];
    const float* Wo = (const float*)d_in[5];

    // ws layout (peak 60 MB; ws >= 64 MB verified r3/r4):
    //   [0,0.5M) ctab  [0.5M,1M) stab
    //   [1M,9M)  ctx  (attn writes rows<2048 direct; merge writes rows>=2048)
    //   [1M,3M) Wtq  [3M,5M) Wtk  [5M,7M) Wtv   (dead before attn)
    //   [9M,11M) Wto
    //   [11M,19M) kr  [19M,27M) vb  [27M,35M) qr  [35M,43M) xb
    //   [43M,59M) Opart (bf16, 2 partitions)  [59M,60M) lpart (f32)
    char* ws = (char*)d_ws;
    float* ctab = (float*)(ws);
    float* stab = (float*)(ws + (512u << 10));
    unsigned short* ctx = (unsigned short*)(ws + (1u  << 20));
    unsigned short* Wtq = (unsigned short*)(ws + (1u  << 20));
    unsigned short* Wtk = (unsigned short*)(ws + (3u  << 20));
    unsigned short* Wtv = (unsigned short*)(ws + (5u  << 20));
    unsigned short* Wto = (unsigned short*)(ws + (9u  << 20));
    unsigned short* kr  = (unsigned short*)(ws + (11u << 20));
    unsigned short* vb  = (unsigned short*)(ws + (19u << 20));
    unsigned short* qr  = (unsigned short*)(ws + (27u << 20));
    unsigned short* xb  = (unsigned short*)(ws + (35u << 20));
    unsigned short* Opart = (unsigned short*)(ws + (43u << 20));
    float* lpart = (float*)(ws + (59u << 20));

    prep_kernel<<<3584, 256, 0, stream>>>(x, Wq, Wk, Wv, Wo, xb,
                                          Wtq, Wtk, Wtv, Wto, ctab, stab);
    gemm_kernel<1><<<dim3(8, 32, 3), 256, 0, stream>>>(xb, Wtq, Wtk, Wtv,
                                                       qr, kr, vb, nullptr, ctab, stab);
    attn_kernel<<<dim3(16, 16, 2), 512, 0, stream>>>(qr, kr, vb, ctx, Opart, lpart);
    attn_merge_kernel<<<(16 * 2048 * 8) / 256, 256, 0, stream>>>(Opart, lpart, ctx);
    gemm_kernel<0><<<dim3(8, 32, 1), 256, 0, stream>>>(ctx, Wto, nullptr, nullptr,
                                                       nullptr, nullptr, nullptr,
                                                       (float*)d_out, ctab, stab);
}